// Round 10
// baseline (227.980 us; speedup 1.0000x reference)
//
#include <hip/hip_runtime.h>

typedef _Float16 half8 __attribute__((ext_vector_type(8)));
typedef float f32x4 __attribute__((ext_vector_type(4)));

#define SPH  32           // timesteps per phase
#define NIT  34           // 32 compute phases + 2 pipeline-drain iterations
#define SPKW 392          // spk row stride f16: 384 + 8 pad (784 B rows; +4 banks/row)
#define XSW  32           // xs row stride (floats)
#define C2W  48           // c2L row stride (floats); wave m=2 writes cols 32..47
#define TN   1000

// Software-pipelined, ONE barrier per iteration (R5 structure). At iteration ph:
//   conv threads (tid<96, wave0 + half wave1): conv+LIF1(ph), TWO channels
//     (c, c+8) per thread -> the same 4 ds_read_b64 window feeds 4 neurons.
//     Halves the dominant LDS term (384 -> 192 b64/iter).  [R5-R9 synthesis:
//     shared-LDS-unit instruction count is the governor; latency/barrier
//     theories falsified by R6/R7; VMEM routes falsified by R8/R9.]
//   waves 0-2: stage x(ph+1) via register bulk loads (as R5)
//   waves 3-5: FC GEMM(ph-1)  [reads spk[(ph-1)&1], writes c2L[(ph-1)&1]]
//   wave 3:    LIF2 scan(ph-2) [reads c2L[(ph-2)&1]], loads hoisted before MFMA
__global__ __launch_bounds__(384, 1) void snn_fwd(
    const float* __restrict__ x,      // (256,1000,30)
    const float* __restrict__ conv_w, // (16,1,7)
    const float* __restrict__ conv_b, // (16)
    const float* __restrict__ fc_w,   // (35,384)
    const float* __restrict__ fc_b,   // (35)
    float* __restrict__ out)          // (256,35)
{
    __shared__ _Float16 spk[2][SPH][SPKW];   // 50176 B
    __shared__ float    xs[2][SPH][XSW];     //  8192 B
    __shared__ float    c2L[2][SPH][C2W];    // 12288 B

    const int tid  = threadIdx.x;
    const int b    = blockIdx.x;
    const int wid  = tid >> 6;
    const int lane = tid & 63;

    // ---------- conv setup: tid<96, thread = (c=tid/12 in 0..7, u=tid%12) ----------
    // owns channels c and c+8, positions 2u and 2u+1 (4 neurons, shared x window)
    const int c  = tid / 12;
    const int u  = tid % 12;
    float wkA[7], wkB[7];
    float cbA = 0.f, cbB = 0.f;
    if (tid < 96) {
#pragma unroll
        for (int k = 0; k < 7; ++k) {
            wkA[k] = conv_w[c * 7 + k];
            wkB[k] = conv_w[(c + 8) * 7 + k];
        }
        cbA = conv_b[c];
        cbB = conv_b[c + 8];
    }

    // ---------- FC-wave setup: A fragments (f16 weights, K=384) ----------
    const int m  = wid - 3;
    const int nL = lane & 15;    // B col (t_local); C col
    const int q  = lane >> 4;    // quad: k = q*8 + j
    half8 A[12];
    if (wid >= 3) {
        const int o = m * 16 + nL;
#pragma unroll
        for (int kt = 0; kt < 12; ++kt) {
            half8 a;
#pragma unroll
            for (int j = 0; j < 8; ++j) {
                int K = kt * 32 + q * 8 + j;
                a[j] = (o < 35) ? (_Float16)fc_w[o * 384 + K] : (_Float16)0.f;
            }
            A[kt] = a;
        }
    }
    const float fcb = (wid == 3 && lane < 35) ? fc_b[lane] : 0.f;

    // ---------- state ----------
    float m1A0 = 0.f, m1A1 = 0.f, m1B0 = 0.f, m1B1 = 0.f;   // LIF1 (4 neurons)
    float spA0 = 0.f, spA1 = 0.f, spB0 = 0.f, spB1 = 0.f;
    float mem2 = 0.f, accO = 0.f;                            // LIF2 (wave3 lanes<35)

    const float* xb = x + (size_t)b * (TN * 30);

    // ---------- prologue: stage xs[0] (960 floats = 192 thr * 5) ----------
    if (wid < 3) {
#pragma unroll
        for (int r = 0; r < 5; ++r) {
            int f = tid + 192 * r;         // 0..959
            xs[0][f / 30][f % 30] = xb[f]; // t < 32 < TN
        }
    }
    __syncthreads();

#pragma unroll 1
    for (int ph = 0; ph < NIT; ++ph) {
        if (wid < 3) {
            float xr[5];
            const bool stg = (ph <= 30);
            if (stg) {                     // issue global loads early (latency overlap)
                const float* src = xb + (ph + 1) * (SPH * 30);
#pragma unroll
                for (int r = 0; r < 5; ++r) {
                    int f = tid + 192 * r;
                    int t = (ph + 1) * SPH + f / 30;
                    xr[r] = (t < TN) ? src[f] : 0.f;
                }
            }
            if (tid < 96 && ph < 32) {
                const float* xrow = &xs[ph & 1][0][2 * u];
                _Float16* sbase = &spk[ph & 1][0][0];
                const int colA = c * 24 + 2 * u;         // f16 index (even)
                const int colB = (c + 8) * 24 + 2 * u;
#pragma unroll 4
                for (int s = 0; s < SPH; ++s) {
                    const float2* x2 = (const float2*)(xrow + s * XSW);
                    float2 a0 = x2[0], a1 = x2[1], a2 = x2[2], a3 = x2[3];
                    float cA0 = cbA, cA1 = cbA, cB0 = cbB, cB1 = cbB;
                    cA0 = fmaf(wkA[0], a0.x, cA0);  cA1 = fmaf(wkA[0], a0.y, cA1);
                    cB0 = fmaf(wkB[0], a0.x, cB0);  cB1 = fmaf(wkB[0], a0.y, cB1);
                    cA0 = fmaf(wkA[1], a0.y, cA0);  cA1 = fmaf(wkA[1], a1.x, cA1);
                    cB0 = fmaf(wkB[1], a0.y, cB0);  cB1 = fmaf(wkB[1], a1.x, cB1);
                    cA0 = fmaf(wkA[2], a1.x, cA0);  cA1 = fmaf(wkA[2], a1.y, cA1);
                    cB0 = fmaf(wkB[2], a1.x, cB0);  cB1 = fmaf(wkB[2], a1.y, cB1);
                    cA0 = fmaf(wkA[3], a1.y, cA0);  cA1 = fmaf(wkA[3], a2.x, cA1);
                    cB0 = fmaf(wkB[3], a1.y, cB0);  cB1 = fmaf(wkB[3], a2.x, cB1);
                    cA0 = fmaf(wkA[4], a2.x, cA0);  cA1 = fmaf(wkA[4], a2.y, cA1);
                    cB0 = fmaf(wkB[4], a2.x, cB0);  cB1 = fmaf(wkB[4], a2.y, cB1);
                    cA0 = fmaf(wkA[5], a2.y, cA0);  cA1 = fmaf(wkA[5], a3.x, cA1);
                    cB0 = fmaf(wkB[5], a2.y, cB0);  cB1 = fmaf(wkB[5], a3.x, cB1);
                    cA0 = fmaf(wkA[6], a3.x, cA0);  cA1 = fmaf(wkA[6], a3.y, cA1);
                    cB0 = fmaf(wkB[6], a3.x, cB0);  cB1 = fmaf(wkB[6], a3.y, cB1);

                    m1A0 = fmaf(0.9f, m1A0, cA0 - spA0);
                    m1A1 = fmaf(0.9f, m1A1, cA1 - spA1);
                    m1B0 = fmaf(0.9f, m1B0, cB0 - spB0);
                    m1B1 = fmaf(0.9f, m1B1, cB1 - spB1);
                    spA0 = (m1A0 > 1.0f) ? 1.0f : 0.0f;
                    spA1 = (m1A1 > 1.0f) ? 1.0f : 0.0f;
                    spB0 = (m1B0 > 1.0f) ? 1.0f : 0.0f;
                    spB1 = (m1B1 > 1.0f) ? 1.0f : 0.0f;
                    unsigned pkA = (m1A0 > 1.0f ? 0x3C00u : 0u) | (m1A1 > 1.0f ? 0x3C000000u : 0u);
                    unsigned pkB = (m1B0 > 1.0f ? 0x3C00u : 0u) | (m1B1 > 1.0f ? 0x3C000000u : 0u);
                    _Float16* srow = sbase + s * SPKW;
                    *(unsigned*)(srow + colA) = pkA;
                    *(unsigned*)(srow + colB) = pkB;
                }
            }
            if (stg) {                     // store staged x into the other buffer
                float* dst = &xs[(ph + 1) & 1][0][0];
#pragma unroll
                for (int r = 0; r < 5; ++r) {
                    int f = tid + 192 * r;
                    dst[(f / 30) * XSW + (f % 30)] = xr[r];
                }
            }
        } else {
            // ---- scan loads hoisted: issue before GEMM so the scan chain
            //      overlaps the MFMA pipe instead of following it ----
            const bool doScan = (wid == 3 && lane < 35 && ph >= 2);
            float v[SPH];
            if (doScan) {
                const float* cs = &c2L[(ph - 2) & 1][0][0];
#pragma unroll
                for (int j = 0; j < SPH; ++j) v[j] = cs[j * C2W + lane];
            }
            if (ph >= 1 && ph <= 32) {     // GEMM on spikes of phase ph-1
                const _Float16* sb = &spk[(ph - 1) & 1][0][0];
                half8 B0[12], B1[12];
#pragma unroll
                for (int kt = 0; kt < 12; ++kt) {
                    B0[kt] = *(const half8*)(sb + nL * SPKW + kt * 32 + q * 8);
                    B1[kt] = *(const half8*)(sb + (16 + nL) * SPKW + kt * 32 + q * 8);
                }
                f32x4 acc0 = {0.f, 0.f, 0.f, 0.f};
                f32x4 acc1 = {0.f, 0.f, 0.f, 0.f};
#pragma unroll
                for (int kt = 0; kt < 12; ++kt) {
                    acc0 = __builtin_amdgcn_mfma_f32_16x16x32_f16(A[kt], B0[kt], acc0, 0, 0, 0);
                    acc1 = __builtin_amdgcn_mfma_f32_16x16x32_f16(A[kt], B1[kt], acc1, 0, 0, 0);
                }
                // C/D: col = lane&15 (t_local), row = q*4+i (o_local)
                float* cd = &c2L[(ph - 1) & 1][0][0];
                *(f32x4*)(cd + nL * C2W + m * 16 + q * 4)        = acc0;
                *(f32x4*)(cd + (16 + nL) * C2W + m * 16 + q * 4) = acc1;
            }
            if (doScan) {                  // LIF2 scan of phase ph-2
                const int tb = (ph - 2) * SPH;
#pragma unroll
                for (int j = 0; j < SPH; ++j) {
                    float r2 = (mem2 > 1.0f) ? 1.0f : 0.0f;
                    mem2 = 0.9f * mem2 + (v[j] + fcb) - r2;
                    if (tb + j < TN) accO += mem2;
                }
            }
        }
        __syncthreads();
    }

    if (wid == 3 && lane < 35) out[b * 35 + lane] = accO * (1.0f / (float)TN);
}

extern "C" void kernel_launch(void* const* d_in, const int* in_sizes, int n_in,
                              void* d_out, int out_size, void* d_ws, size_t ws_size,
                              hipStream_t stream) {
    const float* x      = (const float*)d_in[0];
    const float* conv_w = (const float*)d_in[1];
    const float* conv_b = (const float*)d_in[2];
    const float* fc_w   = (const float*)d_in[3];
    const float* fc_b   = (const float*)d_in[4];
    float* out          = (float*)d_out;

    snn_fwd<<<256, 384, 0, stream>>>(x, conv_w, conv_b, fc_w, fc_b, out);
}

// Round 11
// 167.965 us; speedup vs baseline: 1.3573x; 1.3573x over previous
//
#include <hip/hip_runtime.h>

typedef _Float16 half8 __attribute__((ext_vector_type(8)));
typedef float f32x4 __attribute__((ext_vector_type(4)));

#define SPH  32           // timesteps per phase
#define NIT  34           // 32 compute phases + 2 pipeline-drain iterations
#define SPKW 392          // spk row stride f16: 384 + 8 pad (784 B rows; +4 banks/row)
#define XSW  32           // xs row stride (floats)
#define C2W  48           // c2L row stride (floats)
#define TN   1000

// 768 threads = 12 waves (3 waves/SIMD) -- R11: attack un-hidden latency with
// TLP. R5-R10 synthesis: all counted pipes <30%; rearranging one wave's stream
// (R6), barrier count (R7), VMEM routes (R8/R9), and LDS-inst reduction with
// work concentration (R10) all neutral/regressed. Remaining theory: with only
// 6 waves/CU, stalls on the critical wave are unfillable. This round halves
// per-wave work and doubles co-resident waves:
//   waves 0-5  (384 thr): conv+LIF1(ph), ONE neuron/thread (c=ct/24, p=ct%24);
//                         pure conv -- staging moved off these waves.
//   waves 6-11 (384 thr): FC GEMM(ph-1): wave g=wid-6 does (m=g>>1, tb=g&1):
//                         12 B-frag loads + 12 MFMA + 1 store each.
//                         Also stage xs(ph+1): loads first, stores last.
//   wave 6:    LIF2 scan(ph-2), loads hoisted before GEMM.
// One barrier per iteration; producer->consumer 1 barrier apart, rewrites 2.
__global__ __launch_bounds__(768, 1) void snn_fwd(
    const float* __restrict__ x,      // (256,1000,30)
    const float* __restrict__ conv_w, // (16,1,7)
    const float* __restrict__ conv_b, // (16)
    const float* __restrict__ fc_w,   // (35,384)
    const float* __restrict__ fc_b,   // (35)
    float* __restrict__ out)          // (256,35)
{
    __shared__ _Float16 spk[2][SPH][SPKW];   // 50176 B
    __shared__ float    xs[2][SPH][XSW];     //  8192 B
    __shared__ float    c2L[2][SPH][C2W];    // 12288 B

    const int tid  = threadIdx.x;
    const int b    = blockIdx.x;
    const int wid  = tid >> 6;
    const int lane = tid & 63;

    // ---------- conv setup (wid<6): thread = (c=ct/24, p=ct%24), ONE neuron ----------
    const int ct = tid;              // 0..383 when wid<6
    const int c  = ct / 24;
    const int p  = ct % 24;
    float wk[7];
    float cb = 0.f;
    if (wid < 6) {
#pragma unroll
        for (int k = 0; k < 7; ++k) wk[k] = conv_w[c * 7 + k];
        cb = conv_b[c];
    }

    // ---------- FC setup (wid>=6): g=(wid-6): m=g>>1 (M-tile), tb=g&1 (t-block) ----------
    const int g  = wid - 6;
    const int m  = g >> 1;
    const int tb = g & 1;
    const int nL = lane & 15;        // B col (t_local); C col
    const int q  = lane >> 4;        // quad: k = q*8 + j
    half8 A[12];
    if (wid >= 6) {
        const int o = m * 16 + nL;
#pragma unroll
        for (int kt = 0; kt < 12; ++kt) {
            half8 a;
#pragma unroll
            for (int j = 0; j < 8; ++j) {
                int K = kt * 32 + q * 8 + j;
                a[j] = (o < 35) ? (_Float16)fc_w[o * 384 + K] : (_Float16)0.f;
            }
            A[kt] = a;
        }
    }
    const float fcb = (wid == 6 && lane < 35) ? fc_b[lane] : 0.f;
    const int st = tid - 384;        // staging index 0..383 for wid>=6

    // ---------- state ----------
    float m1 = 0.f, sp = 0.f;        // LIF1 (one neuron)
    float mem2 = 0.f, accO = 0.f;    // LIF2 (wave6 lanes<35)

    const float* xb = x + (size_t)b * (TN * 30);

    // ---------- prologue: stage xs[0] (960 floats; wid>=6, 3 strided each) ----------
    if (wid >= 6) {
#pragma unroll
        for (int r = 0; r < 3; ++r) {
            int f = st + 384 * r;        // 0..1151
            if (f < 960) xs[0][f / 30][f % 30] = xb[f];   // t < 32 < TN
        }
    }
    __syncthreads();

#pragma unroll 1
    for (int ph = 0; ph < NIT; ++ph) {
        if (wid < 6) {
            // =================== conv+LIF1(ph): pure, no staging ===================
            if (ph < 32) {
                const float* xrow = &xs[ph & 1][0][p];
                unsigned short* sdst = (unsigned short*)&spk[ph & 1][0][ct];
#pragma unroll 4
                for (int s = 0; s < SPH; ++s) {
                    const float* xr = xrow + s * XSW;
                    float x0 = xr[0], x1 = xr[1], x2 = xr[2], x3 = xr[3];
                    float x4 = xr[4], x5 = xr[5], x6 = xr[6];
                    float c1 = cb;
                    c1 = fmaf(wk[0], x0, c1);
                    c1 = fmaf(wk[1], x1, c1);
                    c1 = fmaf(wk[2], x2, c1);
                    c1 = fmaf(wk[3], x3, c1);
                    c1 = fmaf(wk[4], x4, c1);
                    c1 = fmaf(wk[5], x5, c1);
                    c1 = fmaf(wk[6], x6, c1);
                    m1 = fmaf(0.9f, m1, c1 - sp);
                    sp = (m1 > 1.0f) ? 1.0f : 0.0f;
                    sdst[s * SPKW] = (m1 > 1.0f) ? (unsigned short)0x3C00u : (unsigned short)0u;
                }
            }
        } else {
            // ====== staging loads for ph+1 issued first (latency overlap) ======
            float xr[3];
            const bool stg = (ph <= 30);
            if (stg) {
                const float* src = xb + (ph + 1) * (SPH * 30);
#pragma unroll
                for (int r = 0; r < 3; ++r) {
                    int f = st + 384 * r;
                    int t = (ph + 1) * SPH + f / 30;
                    xr[r] = (f < 960 && t < TN) ? src[f] : 0.f;
                }
            }
            // ---- scan loads hoisted before MFMA (wave 6 only) ----
            const bool doScan = (wid == 6 && lane < 35 && ph >= 2);
            float v[SPH];
            if (doScan) {
                const float* cs = &c2L[(ph - 2) & 1][0][0];
#pragma unroll
                for (int j = 0; j < SPH; ++j) v[j] = cs[j * C2W + lane];
            }
            // =================== GEMM(ph-1): this wave's (m, tb) ===================
            if (ph >= 1 && ph <= 32) {
                const _Float16* sb = &spk[(ph - 1) & 1][0][0];
                half8 B[12];
#pragma unroll
                for (int kt = 0; kt < 12; ++kt)
                    B[kt] = *(const half8*)(sb + (tb * 16 + nL) * SPKW + kt * 32 + q * 8);
                f32x4 acc = {0.f, 0.f, 0.f, 0.f};
#pragma unroll
                for (int kt = 0; kt < 12; ++kt)
                    acc = __builtin_amdgcn_mfma_f32_16x16x32_f16(A[kt], B[kt], acc, 0, 0, 0);
                // C/D: col = lane&15 (t_local), row = q*4+i (o_local)
                float* cd = &c2L[(ph - 1) & 1][0][0];
                *(f32x4*)(cd + (tb * 16 + nL) * C2W + m * 16 + q * 4) = acc;
            }
            // =================== LIF2 scan(ph-2) (wave 6 lanes<35) ===================
            if (doScan) {
                const int tbase = (ph - 2) * SPH;
#pragma unroll
                for (int j = 0; j < SPH; ++j) {
                    float r2 = (mem2 > 1.0f) ? 1.0f : 0.0f;
                    mem2 = 0.9f * mem2 + (v[j] + fcb) - r2;
                    if (tbase + j < TN) accO += mem2;
                }
            }
            // ====== staging stores for ph+1 (after everything else) ======
            if (stg) {
                float* dst = &xs[(ph + 1) & 1][0][0];
#pragma unroll
                for (int r = 0; r < 3; ++r) {
                    int f = st + 384 * r;
                    if (f < 960) dst[(f / 30) * XSW + (f % 30)] = xr[r];
                }
            }
        }
        __syncthreads();
    }

    if (wid == 6 && lane < 35) out[b * 35 + lane] = accO * (1.0f / (float)TN);
}

extern "C" void kernel_launch(void* const* d_in, const int* in_sizes, int n_in,
                              void* d_out, int out_size, void* d_ws, size_t ws_size,
                              hipStream_t stream) {
    const float* x      = (const float*)d_in[0];
    const float* conv_w = (const float*)d_in[1];
    const float* conv_b = (const float*)d_in[2];
    const float* fc_w   = (const float*)d_in[3];
    const float* fc_b   = (const float*)d_in[4];
    float* out          = (float*)d_out;

    snn_fwd<<<256, 768, 0, stream>>>(x, conv_w, conv_b, fc_w, fc_b, out);
}